// Round 8
// baseline (164.349 us; speedup 1.0000x reference)
//
#include <hip/hip_runtime.h>

typedef unsigned short u16;
typedef unsigned int u32;
typedef __bf16 bf16x8 __attribute__((ext_vector_type(8)));
typedef float f32x4 __attribute__((ext_vector_type(4)));
typedef float f32x8 __attribute__((ext_vector_type(8)));
typedef float f32x16 __attribute__((ext_vector_type(16)));

#define MFMA16(a, b, c) __builtin_amdgcn_mfma_f32_16x16x32_bf16((a), (b), (c), 0, 0, 0)
#define MFMA32(a, b, c) __builtin_amdgcn_mfma_f32_32x32x16_bf16((a), (b), (c), 0, 0, 0)

// Problem constants
#define Bn 4
#define Cn 256
#define Ln 2048
#define Hn 8
#define Dn 64
#define HID 512
#define SEGELEMS 4194304  // elems per attention-partial segment (4*2048*512)

__device__ __forceinline__ u16 bf16_rne(float f) {
  u32 u = __builtin_bit_cast(u32, f);
  u += 0x7FFFu + ((u >> 16) & 1u);
  return (u16)(u >> 16);
}

__device__ __forceinline__ unsigned pack2(float a, float b) {
  return (unsigned)bf16_rne(a) | ((unsigned)bf16_rne(b) << 16);
}

__device__ __forceinline__ float bf16_up(u16 v) {
  u32 u = ((u32)v) << 16;
  return __builtin_bit_cast(float, u);
}

// (up(a_lo)+up(c_lo))*s , (up(a_hi)+up(c_hi))*s -> packed bf16 pair
__device__ __forceinline__ u32 comb2(u32 a, u32 c, float s) {
  float lo = (bf16_up((u16)(a & 0xFFFF)) + bf16_up((u16)(c & 0xFFFF))) * s;
  float hi = (bf16_up((u16)(a >> 16)) + bf16_up((u16)(c >> 16))) * s;
  return pack2(lo, hi);
}

__device__ __forceinline__ float fast_exp2(float x) {
#if __has_builtin(__builtin_amdgcn_exp2f)
  return __builtin_amdgcn_exp2f(x);
#else
  return exp2f(x);
#endif
}

__device__ __forceinline__ float fast_rcp(float x) {
#if __has_builtin(__builtin_amdgcn_rcpf)
  return __builtin_amdgcn_rcpf(x);
#else
  return 1.0f / x;
#endif
}

// async 16B global -> LDS DMA. HW dest = wave-uniform base + lane*16.
__device__ __forceinline__ void async_load16(const u16* g, u16* l) {
  __builtin_amdgcn_global_load_lds(
      (const __attribute__((address_space(1))) void*)g,
      (__attribute__((address_space(3))) void*)l, 16, 0, 0);
}

// ---------------- prep (merged): weights->bf16 AND x transpose ---------------
__global__ __launch_bounds__(256) void prep_all(const float* __restrict__ wqkv,
                                                const float* __restrict__ wout,
                                                const float* __restrict__ x,
                                                u16* __restrict__ wq,
                                                u16* __restrict__ wo,
                                                u16* __restrict__ xT) {
  const int t = threadIdx.x;
  if (blockIdx.x < 2048) {
    int i = blockIdx.x * 256 + t;
    const float QSCALE = 0.125f * 1.44269504088896340736f;  // scale * log2(e)
    if (i < 3 * HID * Cn) {
      float v = wqkv[i];
      if (i < HID * Cn) v *= QSCALE;  // q rows
      wq[i] = bf16_rne(v);
    } else {
      int j = i - 3 * HID * Cn;
      wo[j] = bf16_rne(wout[j]);
    }
    return;
  }
  __shared__ u16 tile[64][72];
  int v = blockIdx.x - 2048;
  const int lt = v & 31, ct = (v >> 5) & 3, b = v >> 7;
  const float* xp = x + ((size_t)b * Cn + ct * 64) * Ln + lt * 64;
  for (int pass = 0; pass < 4; ++pass) {
    int c = pass * 16 + (t >> 4);
    int l4 = (t & 15) * 4;
    float4 vf = *(const float4*)(xp + (size_t)c * Ln + l4);
    tile[l4 + 0][c] = bf16_rne(vf.x);
    tile[l4 + 1][c] = bf16_rne(vf.y);
    tile[l4 + 2][c] = bf16_rne(vf.z);
    tile[l4 + 3][c] = bf16_rne(vf.w);
  }
  __syncthreads();
  u16* op = xT + ((size_t)b * Ln + lt * 64) * Cn + ct * 64;
  for (int pass = 0; pass < 2; ++pass) {
    int id = pass * 256 + t;
    int l = id >> 3, c8 = (id & 7) * 8;
    *(uint4*)(op + (size_t)l * Cn + c8) = *(const uint4*)&tile[l][c8];
  }
}

// ---------------- QKV GEMM (fused Q/K/V per block): one B staging, 3 A tiles -
// V epilogue permutes l-columns (swap bits 2<->3 within each 16) so that the
// attention PV MFMA's k-order matches the S^T C/D lane-native j-order.
__global__ __launch_bounds__(256, 4) void qkv_gemm(const u16* __restrict__ wq,
                                                   const u16* __restrict__ xT,
                                                   u16* __restrict__ qT,
                                                   u16* __restrict__ kT,
                                                   u16* __restrict__ vv) {
  __shared__ u16 Bs[4096];
  __shared__ u16 Aq[4096];
  __shared__ u16 Ak[4096];
  __shared__ u16 Av[4096];
  const int t = threadIdx.x;
  const int nt = blockIdx.x, head = blockIdx.y, b = blockIdx.z;
  const int n0 = nt * 64, m0 = head * 64;
  const int w = t >> 6, lane = t & 63, q = lane >> 4, ln = lane & 15;

  const u16* Bg = xT + ((size_t)b * Ln + n0) * Cn;
  const u16* AgQ = wq + (size_t)m0 * Cn;
  const u16* AgK = wq + (size_t)(512 + m0) * Cn;
  const u16* AgV = wq + (size_t)(1024 + m0) * Cn;

  f32x4 zf = {0.f, 0.f, 0.f, 0.f};
  f32x4 accQ[4], accK[4], accV[4];
  for (int i = 0; i < 4; ++i) { accQ[i] = zf; accK[i] = zf; accV[i] = zf; }

  const int pr0 = w * 8 + (lane >> 3), pr1 = (4 + w) * 8 + (lane >> 3);
  const int pc0 = (lane & 7) ^ (pr0 & 7), pc1 = (lane & 7) ^ (pr1 & 7);

  for (int kk = 0; kk < 4; ++kk) {
    int k0 = kk * 64;
    async_load16(Bg + (size_t)pr0 * Cn + k0 + pc0 * 8, &Bs[w * 512]);
    async_load16(Bg + (size_t)pr1 * Cn + k0 + pc1 * 8, &Bs[(4 + w) * 512]);
    async_load16(AgQ + (size_t)pr0 * Cn + k0 + pc0 * 8, &Aq[w * 512]);
    async_load16(AgQ + (size_t)pr1 * Cn + k0 + pc1 * 8, &Aq[(4 + w) * 512]);
    async_load16(AgK + (size_t)pr0 * Cn + k0 + pc0 * 8, &Ak[w * 512]);
    async_load16(AgK + (size_t)pr1 * Cn + k0 + pc1 * 8, &Ak[(4 + w) * 512]);
    async_load16(AgV + (size_t)pr0 * Cn + k0 + pc0 * 8, &Av[w * 512]);
    async_load16(AgV + (size_t)pr1 * Cn + k0 + pc1 * 8, &Av[(4 + w) * 512]);
    __syncthreads();
    int ar = w * 16 + ln;
    bf16x8 aq0 = *(const bf16x8*)&Aq[ar * 64 + ((q ^ (ln & 7)) * 8)];
    bf16x8 aq1 = *(const bf16x8*)&Aq[ar * 64 + (((q + 4) ^ (ln & 7)) * 8)];
    bf16x8 ak0 = *(const bf16x8*)&Ak[ar * 64 + ((q ^ (ln & 7)) * 8)];
    bf16x8 ak1 = *(const bf16x8*)&Ak[ar * 64 + (((q + 4) ^ (ln & 7)) * 8)];
    bf16x8 av0 = *(const bf16x8*)&Av[ar * 64 + ((q ^ (ln & 7)) * 8)];
    bf16x8 av1 = *(const bf16x8*)&Av[ar * 64 + (((q + 4) ^ (ln & 7)) * 8)];
    for (int n2 = 0; n2 < 4; ++n2) {
      int br = n2 * 16 + ln;
      bf16x8 b0 = *(const bf16x8*)&Bs[br * 64 + ((q ^ (ln & 7)) * 8)];
      bf16x8 b1 = *(const bf16x8*)&Bs[br * 64 + (((q + 4) ^ (ln & 7)) * 8)];
      accQ[n2] = MFMA16(aq0, b0, accQ[n2]);
      accQ[n2] = MFMA16(aq1, b1, accQ[n2]);
      accK[n2] = MFMA16(ak0, b0, accK[n2]);
      accK[n2] = MFMA16(ak1, b1, accK[n2]);
      accV[n2] = MFMA16(av0, b0, accV[n2]);
      accV[n2] = MFMA16(av1, b1, accV[n2]);
    }
    __syncthreads();
  }

  // Epilogues via LDS repack in Bs.
  int od0 = w * 16 + q * 4;
  int cw = od0 >> 3, lo = od0 & 7;
  // ---- Q ----
  for (int n2 = 0; n2 < 4; ++n2) {
    int l = n2 * 16 + ln;
    uint2 pk;
    pk.x = pack2(accQ[n2][0], accQ[n2][1]);
    pk.y = pack2(accQ[n2][2], accQ[n2][3]);
    *(uint2*)&Bs[l * 64 + ((cw ^ (l & 7)) * 8) + lo] = pk;
  }
  __syncthreads();
  {
    u16* dst = qT + (((size_t)b * Hn + head) * Ln + n0) * Dn;
    for (int pass = 0; pass < 2; ++pass) {
      int id = pass * 256 + t;
      int l = id >> 3, c = id & 7;
      *(uint4*)(dst + (size_t)l * Dn + c * 8) =
          *(const uint4*)&Bs[l * 64 + ((c ^ (l & 7)) * 8)];
    }
  }
  __syncthreads();
  // ---- K ----
  for (int n2 = 0; n2 < 4; ++n2) {
    int l = n2 * 16 + ln;
    uint2 pk;
    pk.x = pack2(accK[n2][0], accK[n2][1]);
    pk.y = pack2(accK[n2][2], accK[n2][3]);
    *(uint2*)&Bs[l * 64 + ((cw ^ (l & 7)) * 8) + lo] = pk;
  }
  __syncthreads();
  {
    u16* dst = kT + (((size_t)b * Hn + head) * Ln + n0) * Dn;
    for (int pass = 0; pass < 2; ++pass) {
      int id = pass * 256 + t;
      int l = id >> 3, c = id & 7;
      *(uint4*)(dst + (size_t)l * Dn + c * 8) =
          *(const uint4*)&Bs[l * 64 + ((c ^ (l & 7)) * 8)];
    }
  }
  __syncthreads();
  // ---- V (l-permuted: swap bits 2 and 3 of l) ----
  for (int n2 = 0; n2 < 4; ++n2) {
    int l = n2 * 16 + ln;
    int lpm = (l & ~12) | ((l & 4) << 1) | ((l & 8) >> 1);
    int cl = lpm >> 3, lov = lpm & 7;
    for (int r = 0; r < 4; ++r) {
      int od = w * 16 + q * 4 + r;
      Bs[od * 64 + ((cl ^ (od & 7)) * 8) + lov] = bf16_rne(accV[n2][r]);
    }
  }
  __syncthreads();
  {
    u16* dst = vv + ((size_t)b * HID + head * 64) * Ln + n0;
    for (int pass = 0; pass < 2; ++pass) {
      int id = pass * 256 + t;
      int od = id >> 3, c = id & 7;
      *(uint4*)(dst + (size_t)od * Ln + c * 8) =
          *(const uint4*)&Bs[od * 64 + ((c ^ (od & 7)) * 8)];
    }
  }
}

// ---------------- Flash attention v8: P-in-register + VGPR prefetch pipeline -
// split-K (2 segs), 128 q/block, 32 q/wave, 32x32x16 MFMA. K/V for jt+1 are
// loaded into named VGPRs during compute(jt) (spill-proof macros), so the
// vmcnt drain at each __syncthreads waits on loads that already landed.
__global__ __launch_bounds__(256, 4) void attention(const u16* __restrict__ qT,
                                                    const u16* __restrict__ kT,
                                                    const u16* __restrict__ vv,
                                                    u16* __restrict__ pO,
                                                    float* __restrict__ lP) {
  __shared__ u16 Kt[4096];  // [64 j][64 d], chunk c at c^(j&7)
  __shared__ u16 Vt[4096];  // [64 d][64 jpos], chunk c at c^(d&7)
  const int t = threadIdx.x;
  const int qb = blockIdx.x, bh = blockIdx.y, seg = blockIdx.z;
  const int b = bh >> 3, hh = bh & 7;
  const int w = t >> 6, lane = t & 63;
  const int li = lane & 31, h = lane >> 5;
  const int i0 = qb * 128 + w * 32;

  bf16x8 qf0, qf1, qf2, qf3;
  {
    const u16* qrow = qT + (((size_t)bh) * Ln + i0 + li) * Dn + h * 8;
    qf0 = *(const bf16x8*)(qrow + 0);
    qf1 = *(const bf16x8*)(qrow + 16);
    qf2 = *(const bf16x8*)(qrow + 32);
    qf3 = *(const bf16x8*)(qrow + 48);
  }

  const u16* ksrc0 = kT + ((size_t)bh) * Ln * Dn;
  const u16* vsrc0 = vv + ((size_t)b * HID + hh * Dn) * Ln;

  f32x16 z16;  // persistent zero C-operand
#pragma unroll
  for (int r = 0; r < 16; ++r) z16[r] = 0.f;
  f32x16 o0 = z16, o1 = z16;
  float lp = 0.f;

  const int pr0 = w * 8 + (lane >> 3), pr1 = (4 + w) * 8 + (lane >> 3);
  const int pc0 = (lane & 7) ^ (pr0 & 7), pc1 = (lane & 7) ^ (pr1 & 7);
  const u16* kadr0 = ksrc0 + ((size_t)seg * 1024 + pr0) * Dn + pc0 * 8;
  const u16* kadr1 = ksrc0 + ((size_t)seg * 1024 + pr1) * Dn + pc1 * 8;
  const u16* vadr0 = vsrc0 + (size_t)pr0 * Ln + seg * 1024 + pc0 * 8;
  const u16* vadr1 = vsrc0 + (size_t)pr1 * Ln + seg * 1024 + pc1 * 8;

  const int sw = (li & 7);

#define LOADKV(jt, K0, K1, V0, V1)                              \
  {                                                             \
    int j0_ = (jt) * 64;                                        \
    K0 = *(const uint4*)(kadr0 + (size_t)j0_ * Dn);             \
    K1 = *(const uint4*)(kadr1 + (size_t)j0_ * Dn);             \
    V0 = *(const uint4*)(vadr0 + j0_);                          \
    V1 = *(const uint4*)(vadr1 + j0_);                          \
  }
#define STOREKV(K0, K1, V0, V1)                                 \
  {                                                             \
    *(uint4*)&Kt[w * 512 + lane * 8] = K0;                      \
    *(uint4*)&Kt[(4 + w) * 512 + lane * 8] = K1;                \
    *(uint4*)&Vt[w * 512 + lane * 8] = V0;                      \
    *(uint4*)&Vt[(4 + w) * 512 + lane * 8] = V1;                \
  }

#define COMPUTE()                                                              \
  {                                                                            \
    f32x16 sv0, sv1;                                                           \
    {                                                                          \
      bf16x8 k0 = *(const bf16x8*)&Kt[li * 64 + (((0 + h) ^ sw) * 8)];         \
      bf16x8 k1 = *(const bf16x8*)&Kt[(32 + li) * 64 + (((0 + h) ^ sw) * 8)];  \
      sv0 = MFMA32(k0, qf0, z16);                                              \
      sv1 = MFMA32(k1, qf0, z16);                                              \
    }                                                                          \
    {                                                                          \
      bf16x8 k0 = *(const bf16x8*)&Kt[li * 64 + (((2 + h) ^ sw) * 8)];         \
      bf16x8 k1 = *(const bf16x8*)&Kt[(32 + li) * 64 + (((2 + h) ^ sw) * 8)];  \
      sv0 = MFMA32(k0, qf1, sv0);                                              \
      sv1 = MFMA32(k1, qf1, sv1);                                              \
    }                                                                          \
    {                                                                          \
      bf16x8 k0 = *(const bf16x8*)&Kt[li * 64 + (((4 + h) ^ sw) * 8)];         \
      bf16x8 k1 = *(const bf16x8*)&Kt[(32 + li) * 64 + (((4 + h) ^ sw) * 8)];  \
      sv0 = MFMA32(k0, qf2, sv0);                                              \
      sv1 = MFMA32(k1, qf2, sv1);                                              \
    }                                                                          \
    {                                                                          \
      bf16x8 k0 = *(const bf16x8*)&Kt[li * 64 + (((6 + h) ^ sw) * 8)];         \
      bf16x8 k1 = *(const bf16x8*)&Kt[(32 + li) * 64 + (((6 + h) ^ sw) * 8)];  \
      sv0 = MFMA32(k0, qf3, sv0);                                              \
      sv1 = MFMA32(k1, qf3, sv1);                                              \
    }                                                                          \
    _Pragma("unroll") for (int g = 0; g < 16; ++g) {                           \
      sv0[g] = fast_exp2(sv0[g]);                                              \
      sv1[g] = fast_exp2(sv1[g]);                                              \
      lp += sv0[g] + sv1[g];                                                   \
    }                                                                          \
    f32x8 e0 = __builtin_shufflevector(sv0, sv0, 0, 1, 2, 3, 4, 5, 6, 7);      \
    f32x8 e1 = __builtin_shufflevector(sv0, sv0, 8, 9, 10, 11, 12, 13, 14, 15);\
    f32x8 e2 = __builtin_shufflevector(sv1, sv1, 0, 1, 2, 3, 4, 5, 6, 7);      \
    f32x8 e3 = __builtin_shufflevector(sv1, sv1, 8, 9, 10, 11, 12, 13, 14, 15);\
    bf16x8 pf0 = __builtin_convertvector(e0, bf16x8);                          \
    bf16x8 pf1 = __builtin_convertvector(e1, bf16x8);                          \
    bf16x8 pf2 = __builtin_convertvector(e2, bf16x8);                          \
    bf16x8 pf3 = __builtin_convertvector(e3, bf16x8);                          \
    _Pragma("unroll") for (int jc = 0; jc < 4; ++jc) {                         \
      int ch = 2 * jc + h;                                                     \
      bf16x8 pf = (jc == 0) ? pf0 : (jc == 1) ? pf1 : (jc == 2) ? pf2 : pf3;   \
      bf16x8 vf0 = *(const bf16x8*)&Vt[li * 64 + ((ch ^ sw) * 8)];             \
      bf16x8 vf1 = *(const bf16x8*)&Vt[(32 + li) * 64 + ((ch ^ sw) * 8)];      \
      o0 = MFMA32(pf, vf0, o0);                                                \
      o1 = MFMA32(pf, vf1, o1);                                                \
    }                                                                          \
  }

  uint4 ka0, ka1, va0, va1, kb0, kb1, vb0, vb1;
  LOADKV(0, ka0, ka1, va0, va1);
  for (int jt = 0; jt < 16; jt += 2) {
    if (jt) __syncthreads();
    STOREKV(ka0, ka1, va0, va1);
    __syncthreads();
    LOADKV(jt + 1, kb0, kb1, vb0, vb1);  // lands during COMPUTE(jt)
    COMPUTE();
    __syncthreads();
    STOREKV(kb0, kb1, vb0, vb1);
    __syncthreads();
    if (jt + 2 < 16) LOADKV(jt + 2, ka0, ka1, va0, va1);
    COMPUTE();
  }
#undef LOADKV
#undef STOREKV
#undef COMPUTE

  // l partial: lane li's lp covers its h-half of j; sum with partner.
  float lsum = lp + __shfl_xor(lp, 32);
  if (h == 0)
    lP[(((size_t)seg * Bn + b) * Hn + hh) * Ln + i0 + li] = lsum;
  // O partial, unnormalized bf16, att-layout [b][i][h*64+d]
  u16* po = pO + (size_t)seg * SEGELEMS;
#pragma unroll
  for (int r = 0; r < 16; ++r) {
    int ir = (r & 3) + 8 * (r >> 2) + 4 * h;
    size_t base = ((size_t)b * Ln + i0 + ir) * HID + hh * Dn + li;
    po[base] = bf16_rne(o0[r]);
    po[base + 32] = bf16_rne(o1[r]);
  }
}

// ---------------- out GEMM + fused combine -----------------------------------
// y = wo @ ((O0+O1) diag-normalized by 1/(l0+l1)) + b_out. Each K-block of 64
// is exactly one head, so 1/l is uniform per staged B-row-chunk.
__global__ __launch_bounds__(256, 4) void out_gemm(const u16* __restrict__ wo,
                                                   const u16* __restrict__ pO,
                                                   const float* __restrict__ lP,
                                                   const float* __restrict__ bout,
                                                   float* __restrict__ out) {
  __shared__ u16 As[4096];  // [64 o][64 k]
  __shared__ u16 Bs[2048];  // [32 l][64 k]
  const int t = threadIdx.x;
  const int nt = blockIdx.x, mt = blockIdx.y, b = blockIdx.z;
  const int m0 = mt * 64, n0 = nt * 32;
  const int w = t >> 6, lane = t & 63, q = lane >> 4, ln = lane & 15;

  const u16* Ag = wo + (size_t)m0 * HID;

  f32x4 zf = {0.f, 0.f, 0.f, 0.f};
  f32x4 acc[2];
  acc[0] = zf; acc[1] = zf;

  const int pr0 = w * 8 + (lane >> 3), pr1 = (4 + w) * 8 + (lane >> 3);
  const int pc0 = (lane & 7) ^ (pr0 & 7), pc1 = (lane & 7) ^ (pr1 & 7);
  const u16* Aad0 = Ag + (size_t)pr0 * HID + pc0 * 8;
  const u16* Aad1 = Ag + (size_t)pr1 * HID + pc1 * 8;
  const int irow = n0 + pr0;  // B row (query index) this thread stages
  const u16* Bs0 = pO + ((size_t)b * Ln + irow) * HID + pc0 * 8;
  const u16* Bs1 = Bs0 + SEGELEMS;
  const float* lp0 = lP + (size_t)b * Hn * Ln + irow;
  const float* lp1 = lP + (size_t)(Bn + b) * Hn * Ln + irow;

#define LOADAB(kk, A0, A1, U0, U1, L0, L1)       \
  {                                              \
    int k0_ = (kk) * 64;                         \
    A0 = *(const uint4*)(Aad0 + k0_);            \
    A1 = *(const uint4*)(Aad1 + k0_);            \
    U0 = *(const uint4*)(Bs0 + k0_);             \
    U1 = *(const uint4*)(Bs1 + k0_);             \
    L0 = lp0[(size_t)(kk) * Ln];                 \
    L1 = lp1[(size_t)(kk) * Ln];                 \
  }
#define STOREAB(A0, A1, U0, U1, L0, L1)          \
  {                                              \
    float s_ = fast_rcp(L0 + L1);                \
    uint4 Bc_;                                   \
    Bc_.x = comb2(U0.x, U1.x, s_);               \
    Bc_.y = comb2(U0.y, U1.y, s_);               \
    Bc_.z = comb2(U0.z, U1.z, s_);               \
    Bc_.w = comb2(U0.w, U1.w, s_);               \
    *(uint4*)&As[w * 512 + lane * 8] = A0;       \
    *(uint4*)&As[(4 + w) * 512 + lane * 8] = A1; \
    *(uint4*)&Bs[w * 512 + lane * 8] = Bc_;      \
  }
#define COMPUTEC()                                                             \
  {                                                                            \
    int ar = w * 16 + ln;                                                      \
    bf16x8 a0 = *(const bf16x8*)&As[ar * 64 + ((q ^ (ln & 7)) * 8)];           \
    bf16x8 a1 = *(const bf16x8*)&As[ar * 64 + (((q + 4) ^ (ln & 7)) * 8)];     \
    for (int n2 = 0; n2 < 2; ++n2) {                                           \
      int br = n2 * 16 + ln;                                                   \
      bf16x8 b0 = *(const bf16x8*)&Bs[br * 64 + ((q ^ (ln & 7)) * 8)];         \
      bf16x8 b1 = *(const bf16x8*)&Bs[br * 64 + (((q + 4) ^ (ln & 7)) * 8)];   \
      acc[n2] = MFMA16(a0, b0, acc[n2]);                                       \
      acc[n2] = MFMA16(a1, b1, acc[n2]);                                       \
    }                                                                          \
  }

  uint4 aa0, aa1, ua0, ua1, ab0, ab1, ub0, ub1;
  float la0, la1, lb0, lb1;
  LOADAB(0, aa0, aa1, ua0, ua1, la0, la1);
  for (int kk = 0; kk < 8; kk += 2) {
    if (kk) __syncthreads();
    STOREAB(aa0, aa1, ua0, ua1, la0, la1);
    __syncthreads();
    LOADAB(kk + 1, ab0, ab1, ub0, ub1, lb0, lb1);
    COMPUTEC();
    __syncthreads();
    STOREAB(ab0, ab1, ub0, ub1, lb0, lb1);
    __syncthreads();
    if (kk + 2 < 8) LOADAB(kk + 2, aa0, aa1, ua0, ua1, la0, la1);
    COMPUTEC();
  }
#undef LOADAB
#undef STOREAB
#undef COMPUTEC

  float bias[4];
  for (int r = 0; r < 4; ++r) bias[r] = bout[m0 + w * 16 + q * 4 + r];
  for (int n2 = 0; n2 < 2; ++n2) {
    int l = n0 + n2 * 16 + ln;
    for (int r = 0; r < 4; ++r) {
      int o = m0 + w * 16 + q * 4 + r;
      out[((size_t)b * Cn + o) * Ln + l] = acc[n2][r] + bias[r];
    }
  }
}

// ---------------- launch -----------------------------------------------------
extern "C" void kernel_launch(void* const* d_in, const int* in_sizes, int n_in,
                              void* d_out, int out_size, void* d_ws, size_t ws_size,
                              hipStream_t stream) {
  const float* x = (const float*)d_in[0];
  const float* wqkv = (const float*)d_in[1];
  const float* wout = (const float*)d_in[2];
  const float* bout = (const float*)d_in[3];
  float* out = (float*)d_out;
  char* ws = (char*)d_ws;

  u16* wq_b  = (u16*)(ws + 0);          // [1536][256] bf16          (786432)
  u16* wo_b  = (u16*)(ws + 786432);     // [256][512]  bf16          (262144)
  float* lP  = (float*)(ws + 1048576);  // [2][4][8][2048] f32       (524288)
  u16* qT    = (u16*)(ws + 1572864);    // [4][8][2048][64]          (8 MB)
  u16* kT    = (u16*)(ws + 9961472);    // [4][8][2048][64]          (8 MB)
  u16* vv    = (u16*)(ws + 18350080);   // [4][512][2048] (l-permuted) (8 MB)
  u16* xT    = (u16*)(ws + 26738688);   // [4][2048][256]            (4 MB)
  u16* pO    = (u16*)(ws + 26738688);   // [2][4][2048][512]         (16 MB)

  prep_all<<<2560, 256, 0, stream>>>(wqkv, wout, x, wq_b, wo_b, xT);
  qkv_gemm<<<dim3(32, 8, 4), 256, 0, stream>>>(wq_b, xT, qT, kT, vv);
  attention<<<dim3(16, 32, 2), 256, 0, stream>>>(qT, kT, vv, pO, lP);
  out_gemm<<<dim3(64, 4, 4), 256, 0, stream>>>(wo_b, pO, lP, bout, out);
}

// Round 9
// 135.397 us; speedup vs baseline: 1.2138x; 1.2138x over previous
//
#include <hip/hip_runtime.h>

typedef unsigned short u16;
typedef unsigned int u32;
typedef __bf16 bf16x8 __attribute__((ext_vector_type(8)));
typedef float f32x4 __attribute__((ext_vector_type(4)));
typedef float f32x8 __attribute__((ext_vector_type(8)));
typedef float f32x16 __attribute__((ext_vector_type(16)));

#define MFMA16(a, b, c) __builtin_amdgcn_mfma_f32_16x16x32_bf16((a), (b), (c), 0, 0, 0)
#define MFMA32(a, b, c) __builtin_amdgcn_mfma_f32_32x32x16_bf16((a), (b), (c), 0, 0, 0)

// Problem constants
#define Bn 4
#define Cn 256
#define Ln 2048
#define Hn 8
#define Dn 64
#define HID 512
#define SEGELEMS 4194304  // elems per attention-partial segment (4*2048*512)

__device__ __forceinline__ u16 bf16_rne(float f) {
  u32 u = __builtin_bit_cast(u32, f);
  u += 0x7FFFu + ((u >> 16) & 1u);
  return (u16)(u >> 16);
}

__device__ __forceinline__ unsigned pack2(float a, float b) {
  return (unsigned)bf16_rne(a) | ((unsigned)bf16_rne(b) << 16);
}

__device__ __forceinline__ float bf16_up(u16 v) {
  u32 u = ((u32)v) << 16;
  return __builtin_bit_cast(float, u);
}

// (up(a_lo)+up(c_lo))*s , (up(a_hi)+up(c_hi))*s -> packed bf16 pair
__device__ __forceinline__ u32 comb2(u32 a, u32 c, float s) {
  float lo = (bf16_up((u16)(a & 0xFFFF)) + bf16_up((u16)(c & 0xFFFF))) * s;
  float hi = (bf16_up((u16)(a >> 16)) + bf16_up((u16)(c >> 16))) * s;
  return pack2(lo, hi);
}

__device__ __forceinline__ float fast_exp2(float x) {
#if __has_builtin(__builtin_amdgcn_exp2f)
  return __builtin_amdgcn_exp2f(x);
#else
  return exp2f(x);
#endif
}

__device__ __forceinline__ float fast_rcp(float x) {
#if __has_builtin(__builtin_amdgcn_rcpf)
  return __builtin_amdgcn_rcpf(x);
#else
  return 1.0f / x;
#endif
}

// async 16B global -> LDS DMA. HW dest = wave-uniform base + lane*16.
__device__ __forceinline__ void async_load16(const u16* g, u16* l) {
  __builtin_amdgcn_global_load_lds(
      (const __attribute__((address_space(1))) void*)g,
      (__attribute__((address_space(3))) void*)l, 16, 0, 0);
}

// ---------------- prep (merged): weights->bf16 AND x transpose ---------------
__global__ __launch_bounds__(256) void prep_all(const float* __restrict__ wqkv,
                                                const float* __restrict__ wout,
                                                const float* __restrict__ x,
                                                u16* __restrict__ wq,
                                                u16* __restrict__ wo,
                                                u16* __restrict__ xT) {
  const int t = threadIdx.x;
  if (blockIdx.x < 2048) {
    int i = blockIdx.x * 256 + t;
    const float QSCALE = 0.125f * 1.44269504088896340736f;  // scale * log2(e)
    if (i < 3 * HID * Cn) {
      float v = wqkv[i];
      if (i < HID * Cn) v *= QSCALE;  // q rows
      wq[i] = bf16_rne(v);
    } else {
      int j = i - 3 * HID * Cn;
      wo[j] = bf16_rne(wout[j]);
    }
    return;
  }
  __shared__ u16 tile[64][72];
  int v = blockIdx.x - 2048;
  const int lt = v & 31, ct = (v >> 5) & 3, b = v >> 7;
  const float* xp = x + ((size_t)b * Cn + ct * 64) * Ln + lt * 64;
  for (int pass = 0; pass < 4; ++pass) {
    int c = pass * 16 + (t >> 4);
    int l4 = (t & 15) * 4;
    float4 vf = *(const float4*)(xp + (size_t)c * Ln + l4);
    tile[l4 + 0][c] = bf16_rne(vf.x);
    tile[l4 + 1][c] = bf16_rne(vf.y);
    tile[l4 + 2][c] = bf16_rne(vf.z);
    tile[l4 + 3][c] = bf16_rne(vf.w);
  }
  __syncthreads();
  u16* op = xT + ((size_t)b * Ln + lt * 64) * Cn + ct * 64;
  for (int pass = 0; pass < 2; ++pass) {
    int id = pass * 256 + t;
    int l = id >> 3, c8 = (id & 7) * 8;
    *(uint4*)(op + (size_t)l * Cn + c8) = *(const uint4*)&tile[l][c8];
  }
}

// ---------------- QKV GEMM (fused Q/K/V per block): one B staging, 3 A tiles -
// V epilogue permutes l-columns (swap bits 2<->3 within each 16) so that the
// attention PV MFMA's k-order matches the S^T C/D lane-native j-order.
__global__ __launch_bounds__(256, 4) void qkv_gemm(const u16* __restrict__ wq,
                                                   const u16* __restrict__ xT,
                                                   u16* __restrict__ qT,
                                                   u16* __restrict__ kT,
                                                   u16* __restrict__ vv) {
  __shared__ u16 Bs[4096];
  __shared__ u16 Aq[4096];
  __shared__ u16 Ak[4096];
  __shared__ u16 Av[4096];
  const int t = threadIdx.x;
  const int nt = blockIdx.x, head = blockIdx.y, b = blockIdx.z;
  const int n0 = nt * 64, m0 = head * 64;
  const int w = t >> 6, lane = t & 63, q = lane >> 4, ln = lane & 15;

  const u16* Bg = xT + ((size_t)b * Ln + n0) * Cn;
  const u16* AgQ = wq + (size_t)m0 * Cn;
  const u16* AgK = wq + (size_t)(512 + m0) * Cn;
  const u16* AgV = wq + (size_t)(1024 + m0) * Cn;

  f32x4 zf = {0.f, 0.f, 0.f, 0.f};
  f32x4 accQ[4], accK[4], accV[4];
  for (int i = 0; i < 4; ++i) { accQ[i] = zf; accK[i] = zf; accV[i] = zf; }

  const int pr0 = w * 8 + (lane >> 3), pr1 = (4 + w) * 8 + (lane >> 3);
  const int pc0 = (lane & 7) ^ (pr0 & 7), pc1 = (lane & 7) ^ (pr1 & 7);

  for (int kk = 0; kk < 4; ++kk) {
    int k0 = kk * 64;
    async_load16(Bg + (size_t)pr0 * Cn + k0 + pc0 * 8, &Bs[w * 512]);
    async_load16(Bg + (size_t)pr1 * Cn + k0 + pc1 * 8, &Bs[(4 + w) * 512]);
    async_load16(AgQ + (size_t)pr0 * Cn + k0 + pc0 * 8, &Aq[w * 512]);
    async_load16(AgQ + (size_t)pr1 * Cn + k0 + pc1 * 8, &Aq[(4 + w) * 512]);
    async_load16(AgK + (size_t)pr0 * Cn + k0 + pc0 * 8, &Ak[w * 512]);
    async_load16(AgK + (size_t)pr1 * Cn + k0 + pc1 * 8, &Ak[(4 + w) * 512]);
    async_load16(AgV + (size_t)pr0 * Cn + k0 + pc0 * 8, &Av[w * 512]);
    async_load16(AgV + (size_t)pr1 * Cn + k0 + pc1 * 8, &Av[(4 + w) * 512]);
    __syncthreads();
    int ar = w * 16 + ln;
    bf16x8 aq0 = *(const bf16x8*)&Aq[ar * 64 + ((q ^ (ln & 7)) * 8)];
    bf16x8 aq1 = *(const bf16x8*)&Aq[ar * 64 + (((q + 4) ^ (ln & 7)) * 8)];
    bf16x8 ak0 = *(const bf16x8*)&Ak[ar * 64 + ((q ^ (ln & 7)) * 8)];
    bf16x8 ak1 = *(const bf16x8*)&Ak[ar * 64 + (((q + 4) ^ (ln & 7)) * 8)];
    bf16x8 av0 = *(const bf16x8*)&Av[ar * 64 + ((q ^ (ln & 7)) * 8)];
    bf16x8 av1 = *(const bf16x8*)&Av[ar * 64 + (((q + 4) ^ (ln & 7)) * 8)];
    for (int n2 = 0; n2 < 4; ++n2) {
      int br = n2 * 16 + ln;
      bf16x8 b0 = *(const bf16x8*)&Bs[br * 64 + ((q ^ (ln & 7)) * 8)];
      bf16x8 b1 = *(const bf16x8*)&Bs[br * 64 + (((q + 4) ^ (ln & 7)) * 8)];
      accQ[n2] = MFMA16(aq0, b0, accQ[n2]);
      accQ[n2] = MFMA16(aq1, b1, accQ[n2]);
      accK[n2] = MFMA16(ak0, b0, accK[n2]);
      accK[n2] = MFMA16(ak1, b1, accK[n2]);
      accV[n2] = MFMA16(av0, b0, accV[n2]);
      accV[n2] = MFMA16(av1, b1, accV[n2]);
    }
    __syncthreads();
  }

  // Epilogues via LDS repack in Bs.
  int od0 = w * 16 + q * 4;
  int cw = od0 >> 3, lo = od0 & 7;
  // ---- Q ----
  for (int n2 = 0; n2 < 4; ++n2) {
    int l = n2 * 16 + ln;
    uint2 pk;
    pk.x = pack2(accQ[n2][0], accQ[n2][1]);
    pk.y = pack2(accQ[n2][2], accQ[n2][3]);
    *(uint2*)&Bs[l * 64 + ((cw ^ (l & 7)) * 8) + lo] = pk;
  }
  __syncthreads();
  {
    u16* dst = qT + (((size_t)b * Hn + head) * Ln + n0) * Dn;
    for (int pass = 0; pass < 2; ++pass) {
      int id = pass * 256 + t;
      int l = id >> 3, c = id & 7;
      *(uint4*)(dst + (size_t)l * Dn + c * 8) =
          *(const uint4*)&Bs[l * 64 + ((c ^ (l & 7)) * 8)];
    }
  }
  __syncthreads();
  // ---- K ----
  for (int n2 = 0; n2 < 4; ++n2) {
    int l = n2 * 16 + ln;
    uint2 pk;
    pk.x = pack2(accK[n2][0], accK[n2][1]);
    pk.y = pack2(accK[n2][2], accK[n2][3]);
    *(uint2*)&Bs[l * 64 + ((cw ^ (l & 7)) * 8) + lo] = pk;
  }
  __syncthreads();
  {
    u16* dst = kT + (((size_t)b * Hn + head) * Ln + n0) * Dn;
    for (int pass = 0; pass < 2; ++pass) {
      int id = pass * 256 + t;
      int l = id >> 3, c = id & 7;
      *(uint4*)(dst + (size_t)l * Dn + c * 8) =
          *(const uint4*)&Bs[l * 64 + ((c ^ (l & 7)) * 8)];
    }
  }
  __syncthreads();
  // ---- V (l-permuted: swap bits 2 and 3 of l) ----
  for (int n2 = 0; n2 < 4; ++n2) {
    int l = n2 * 16 + ln;
    int lpm = (l & ~12) | ((l & 4) << 1) | ((l & 8) >> 1);
    int cl = lpm >> 3, lov = lpm & 7;
    for (int r = 0; r < 4; ++r) {
      int od = w * 16 + q * 4 + r;
      Bs[od * 64 + ((cl ^ (od & 7)) * 8) + lov] = bf16_rne(accV[n2][r]);
    }
  }
  __syncthreads();
  {
    u16* dst = vv + ((size_t)b * HID + head * 64) * Ln + n0;
    for (int pass = 0; pass < 2; ++pass) {
      int id = pass * 256 + t;
      int od = id >> 3, c = id & 7;
      *(uint4*)(dst + (size_t)od * Ln + c * 8) =
          *(const uint4*)&Bs[od * 64 + ((c ^ (od & 7)) * 8)];
    }
  }
}

// ---------------- Flash attention v9: 64 q/wave, 128-thread blocks -----------
// split-K (2 segs), 128 q/block (2 waves x 64 q), 32x32x16 MFMA, P-in-register.
// Each K/V fragment read now feeds 4 MFMAs (2 query-halves) -> DS reads halved
// vs v7. DMA staging (global_load_lds) keeps VGPR pressure off the staging
// path; launch_bounds(128,2) gives a 256-VGPR cap (no spill; R8's (256,4)
// 128-cap + 32 prefetch regs caused the 151 MB scratch-spill regression).
__global__ __launch_bounds__(128, 2) void attention(const u16* __restrict__ qT,
                                                    const u16* __restrict__ kT,
                                                    const u16* __restrict__ vv,
                                                    u16* __restrict__ pO,
                                                    float* __restrict__ lP) {
  __shared__ u16 Kt[4096];  // [64 j][64 d], chunk c at c^(j&7)
  __shared__ u16 Vt[4096];  // [64 d][64 jpos], chunk c at c^(d&7)
  const int t = threadIdx.x;
  const int qb = blockIdx.x, bh = blockIdx.y, seg = blockIdx.z;
  const int b = bh >> 3, hh = bh & 7;
  const int w = t >> 6, lane = t & 63;
  const int li = lane & 31, h = lane >> 5;
  const int i0 = qb * 128 + w * 64;  // this wave's 64 queries

  // Q B-frags for both 32-query halves
  bf16x8 qA0, qA1, qA2, qA3, qB0, qB1, qB2, qB3;
  {
    const u16* qra = qT + (((size_t)bh) * Ln + i0 + li) * Dn + h * 8;
    const u16* qrb = qT + (((size_t)bh) * Ln + i0 + 32 + li) * Dn + h * 8;
    qA0 = *(const bf16x8*)(qra + 0);
    qA1 = *(const bf16x8*)(qra + 16);
    qA2 = *(const bf16x8*)(qra + 32);
    qA3 = *(const bf16x8*)(qra + 48);
    qB0 = *(const bf16x8*)(qrb + 0);
    qB1 = *(const bf16x8*)(qrb + 16);
    qB2 = *(const bf16x8*)(qrb + 32);
    qB3 = *(const bf16x8*)(qrb + 48);
  }

  const u16* ksrc0 = kT + ((size_t)bh) * Ln * Dn;
  const u16* vsrc0 = vv + ((size_t)b * HID + hh * Dn) * Ln;

  f32x16 z16;  // persistent zero C-operand
#pragma unroll
  for (int r = 0; r < 16; ++r) z16[r] = 0.f;
  f32x16 oA0 = z16, oA1 = z16, oB0 = z16, oB1 = z16;
  float lpA = 0.f, lpB = 0.f;

  // staging: 4 issues/thread per tile; issue is -> region reg = is*2+w,
  // row r = reg*8+(lane>>3), chunk c = (lane&7)^(r&7), dest = reg*512 u16.
  const int sr0 = (0 * 2 + w) * 8 + (lane >> 3);
  const int sr1 = (1 * 2 + w) * 8 + (lane >> 3);
  const int sr2 = (2 * 2 + w) * 8 + (lane >> 3);
  const int sr3 = (3 * 2 + w) * 8 + (lane >> 3);
  const int sc0 = (lane & 7) ^ (sr0 & 7), sc1 = (lane & 7) ^ (sr1 & 7);
  const int sc2 = (lane & 7) ^ (sr2 & 7), sc3 = (lane & 7) ^ (sr3 & 7);
  const u16* ka0 = ksrc0 + ((size_t)seg * 1024 + sr0) * Dn + sc0 * 8;
  const u16* ka1 = ksrc0 + ((size_t)seg * 1024 + sr1) * Dn + sc1 * 8;
  const u16* ka2 = ksrc0 + ((size_t)seg * 1024 + sr2) * Dn + sc2 * 8;
  const u16* ka3 = ksrc0 + ((size_t)seg * 1024 + sr3) * Dn + sc3 * 8;
  const u16* va0 = vsrc0 + (size_t)sr0 * Ln + seg * 1024 + sc0 * 8;
  const u16* va1 = vsrc0 + (size_t)sr1 * Ln + seg * 1024 + sc1 * 8;
  const u16* va2 = vsrc0 + (size_t)sr2 * Ln + seg * 1024 + sc2 * 8;
  const u16* va3 = vsrc0 + (size_t)sr3 * Ln + seg * 1024 + sc3 * 8;

  const int sw = li & 7;

  for (int jt = 0; jt < 16; ++jt) {
    int j0 = jt * 64;
    async_load16(ka0 + (size_t)j0 * Dn, &Kt[(0 * 2 + w) * 512]);
    async_load16(ka1 + (size_t)j0 * Dn, &Kt[(1 * 2 + w) * 512]);
    async_load16(ka2 + (size_t)j0 * Dn, &Kt[(2 * 2 + w) * 512]);
    async_load16(ka3 + (size_t)j0 * Dn, &Kt[(3 * 2 + w) * 512]);
    async_load16(va0 + j0, &Vt[(0 * 2 + w) * 512]);
    async_load16(va1 + j0, &Vt[(1 * 2 + w) * 512]);
    async_load16(va2 + j0, &Vt[(2 * 2 + w) * 512]);
    async_load16(va3 + j0, &Vt[(3 * 2 + w) * 512]);
    __syncthreads();  // drains DMA before compute

    // S^T = K·Q^T: each k-frag pair feeds 4 MFMAs (2 j-tiles x 2 q-halves)
    f32x16 svA0, svA1, svB0, svB1;
    {
      bf16x8 k0 = *(const bf16x8*)&Kt[li * 64 + (((0 + h) ^ sw) * 8)];
      bf16x8 k1 = *(const bf16x8*)&Kt[(32 + li) * 64 + (((0 + h) ^ sw) * 8)];
      svA0 = MFMA32(k0, qA0, z16);
      svA1 = MFMA32(k1, qA0, z16);
      svB0 = MFMA32(k0, qB0, z16);
      svB1 = MFMA32(k1, qB0, z16);
    }
    {
      bf16x8 k0 = *(const bf16x8*)&Kt[li * 64 + (((2 + h) ^ sw) * 8)];
      bf16x8 k1 = *(const bf16x8*)&Kt[(32 + li) * 64 + (((2 + h) ^ sw) * 8)];
      svA0 = MFMA32(k0, qA1, svA0);
      svA1 = MFMA32(k1, qA1, svA1);
      svB0 = MFMA32(k0, qB1, svB0);
      svB1 = MFMA32(k1, qB1, svB1);
    }
    {
      bf16x8 k0 = *(const bf16x8*)&Kt[li * 64 + (((4 + h) ^ sw) * 8)];
      bf16x8 k1 = *(const bf16x8*)&Kt[(32 + li) * 64 + (((4 + h) ^ sw) * 8)];
      svA0 = MFMA32(k0, qA2, svA0);
      svA1 = MFMA32(k1, qA2, svA1);
      svB0 = MFMA32(k0, qB2, svB0);
      svB1 = MFMA32(k1, qB2, svB1);
    }
    {
      bf16x8 k0 = *(const bf16x8*)&Kt[li * 64 + (((6 + h) ^ sw) * 8)];
      bf16x8 k1 = *(const bf16x8*)&Kt[(32 + li) * 64 + (((6 + h) ^ sw) * 8)];
      svA0 = MFMA32(k0, qA3, svA0);
      svA1 = MFMA32(k1, qA3, svA1);
      svB0 = MFMA32(k0, qB3, svB0);
      svB1 = MFMA32(k1, qB3, svB1);
    }

    // P = exp2(S) in place; per-lane row sums (column i = this lane)
#pragma unroll
    for (int g = 0; g < 16; ++g) {
      svA0[g] = fast_exp2(svA0[g]);
      svA1[g] = fast_exp2(svA1[g]);
      lpA += svA0[g] + svA1[g];
      svB0[g] = fast_exp2(svB0[g]);
      svB1[g] = fast_exp2(svB1[g]);
      lpB += svB0[g] + svB1[g];
    }
    bf16x8 pfA0 = __builtin_convertvector(
        __builtin_shufflevector(svA0, svA0, 0, 1, 2, 3, 4, 5, 6, 7), bf16x8);
    bf16x8 pfA1 = __builtin_convertvector(
        __builtin_shufflevector(svA0, svA0, 8, 9, 10, 11, 12, 13, 14, 15), bf16x8);
    bf16x8 pfA2 = __builtin_convertvector(
        __builtin_shufflevector(svA1, svA1, 0, 1, 2, 3, 4, 5, 6, 7), bf16x8);
    bf16x8 pfA3 = __builtin_convertvector(
        __builtin_shufflevector(svA1, svA1, 8, 9, 10, 11, 12, 13, 14, 15), bf16x8);
    bf16x8 pfB0 = __builtin_convertvector(
        __builtin_shufflevector(svB0, svB0, 0, 1, 2, 3, 4, 5, 6, 7), bf16x8);
    bf16x8 pfB1 = __builtin_convertvector(
        __builtin_shufflevector(svB0, svB0, 8, 9, 10, 11, 12, 13, 14, 15), bf16x8);
    bf16x8 pfB2 = __builtin_convertvector(
        __builtin_shufflevector(svB1, svB1, 0, 1, 2, 3, 4, 5, 6, 7), bf16x8);
    bf16x8 pfB3 = __builtin_convertvector(
        __builtin_shufflevector(svB1, svB1, 8, 9, 10, 11, 12, 13, 14, 15), bf16x8);

    // O += P·V: each v-frag pair feeds 4 MFMAs (2 d-tiles x 2 q-halves)
#pragma unroll
    for (int jc = 0; jc < 4; ++jc) {
      int ch = 2 * jc + h;
      bf16x8 pa = (jc == 0) ? pfA0 : (jc == 1) ? pfA1 : (jc == 2) ? pfA2 : pfA3;
      bf16x8 pb = (jc == 0) ? pfB0 : (jc == 1) ? pfB1 : (jc == 2) ? pfB2 : pfB3;
      bf16x8 vf0 = *(const bf16x8*)&Vt[li * 64 + ((ch ^ sw) * 8)];
      bf16x8 vf1 = *(const bf16x8*)&Vt[(32 + li) * 64 + ((ch ^ sw) * 8)];
      oA0 = MFMA32(pa, vf0, oA0);
      oA1 = MFMA32(pa, vf1, oA1);
      oB0 = MFMA32(pb, vf0, oB0);
      oB1 = MFMA32(pb, vf1, oB1);
    }
    __syncthreads();  // compute done before next iter's DMA lands
  }

  // l partials (lane li covers its h-half of j; sum with partner lane)
  float lsA = lpA + __shfl_xor(lpA, 32);
  float lsB = lpB + __shfl_xor(lpB, 32);
  if (h == 0) {
    size_t lbase = (((size_t)seg * Bn + b) * Hn + hh) * Ln + i0 + li;
    lP[lbase] = lsA;
    lP[lbase + 32] = lsB;
  }
  // O partials, unnormalized bf16, att-layout [b][i][h*64+d]
  u16* po = pO + (size_t)seg * SEGELEMS;
#pragma unroll
  for (int r = 0; r < 16; ++r) {
    int ir = (r & 3) + 8 * (r >> 2) + 4 * h;
    size_t baseA = ((size_t)b * Ln + i0 + ir) * HID + hh * Dn + li;
    po[baseA] = bf16_rne(oA0[r]);
    po[baseA + 32] = bf16_rne(oA1[r]);
    size_t baseB = ((size_t)b * Ln + i0 + 32 + ir) * HID + hh * Dn + li;
    po[baseB] = bf16_rne(oB0[r]);
    po[baseB + 32] = bf16_rne(oB1[r]);
  }
}

// ---------------- out GEMM + fused combine -----------------------------------
// y = wo @ ((O0+O1) diag-normalized by 1/(l0+l1)) + b_out. Each K-block of 64
// is exactly one head, so 1/l is uniform per staged B-row-chunk.
__global__ __launch_bounds__(256, 4) void out_gemm(const u16* __restrict__ wo,
                                                   const u16* __restrict__ pO,
                                                   const float* __restrict__ lP,
                                                   const float* __restrict__ bout,
                                                   float* __restrict__ out) {
  __shared__ u16 As[4096];  // [64 o][64 k]
  __shared__ u16 Bs[2048];  // [32 l][64 k]
  const int t = threadIdx.x;
  const int nt = blockIdx.x, mt = blockIdx.y, b = blockIdx.z;
  const int m0 = mt * 64, n0 = nt * 32;
  const int w = t >> 6, lane = t & 63, q = lane >> 4, ln = lane & 15;

  const u16* Ag = wo + (size_t)m0 * HID;

  f32x4 zf = {0.f, 0.f, 0.f, 0.f};
  f32x4 acc[2];
  acc[0] = zf; acc[1] = zf;

  const int pr0 = w * 8 + (lane >> 3), pr1 = (4 + w) * 8 + (lane >> 3);
  const int pc0 = (lane & 7) ^ (pr0 & 7), pc1 = (lane & 7) ^ (pr1 & 7);
  const u16* Aad0 = Ag + (size_t)pr0 * HID + pc0 * 8;
  const u16* Aad1 = Ag + (size_t)pr1 * HID + pc1 * 8;
  const int irow = n0 + pr0;  // B row (query index) this thread stages
  const u16* Bs0 = pO + ((size_t)b * Ln + irow) * HID + pc0 * 8;
  const u16* Bs1 = Bs0 + SEGELEMS;
  const float* lp0 = lP + (size_t)b * Hn * Ln + irow;
  const float* lp1 = lP + (size_t)(Bn + b) * Hn * Ln + irow;

#define LOADAB(kk, A0, A1, U0, U1, L0, L1)       \
  {                                              \
    int k0_ = (kk) * 64;                         \
    A0 = *(const uint4*)(Aad0 + k0_);            \
    A1 = *(const uint4*)(Aad1 + k0_);            \
    U0 = *(const uint4*)(Bs0 + k0_);             \
    U1 = *(const uint4*)(Bs1 + k0_);             \
    L0 = lp0[(size_t)(kk) * Ln];                 \
    L1 = lp1[(size_t)(kk) * Ln];                 \
  }
#define STOREAB(A0, A1, U0, U1, L0, L1)          \
  {                                              \
    float s_ = fast_rcp(L0 + L1);                \
    uint4 Bc_;                                   \
    Bc_.x = comb2(U0.x, U1.x, s_);               \
    Bc_.y = comb2(U0.y, U1.y, s_);               \
    Bc_.z = comb2(U0.z, U1.z, s_);               \
    Bc_.w = comb2(U0.w, U1.w, s_);               \
    *(uint4*)&As[w * 512 + lane * 8] = A0;       \
    *(uint4*)&As[(4 + w) * 512 + lane * 8] = A1; \
    *(uint4*)&Bs[w * 512 + lane * 8] = Bc_;      \
  }
#define COMPUTEC()                                                             \
  {                                                                            \
    int ar = w * 16 + ln;                                                      \
    bf16x8 a0 = *(const bf16x8*)&As[ar * 64 + ((q ^ (ln & 7)) * 8)];           \
    bf16x8 a1 = *(const bf16x8*)&As[ar * 64 + (((q + 4) ^ (ln & 7)) * 8)];     \
    for (int n2 = 0; n2 < 2; ++n2) {                                           \
      int br = n2 * 16 + ln;                                                   \
      bf16x8 b0 = *(const bf16x8*)&Bs[br * 64 + ((q ^ (ln & 7)) * 8)];         \
      bf16x8 b1 = *(const bf16x8*)&Bs[br * 64 + (((q + 4) ^ (ln & 7)) * 8)];   \
      acc[n2] = MFMA16(a0, b0, acc[n2]);                                       \
      acc[n2] = MFMA16(a1, b1, acc[n2]);                                       \
    }                                                                          \
  }

  uint4 aa0, aa1, ua0, ua1, ab0, ab1, ub0, ub1;
  float la0, la1, lb0, lb1;
  LOADAB(0, aa0, aa1, ua0, ua1, la0, la1);
  for (int kk = 0; kk < 8; kk += 2) {
    if (kk) __syncthreads();
    STOREAB(aa0, aa1, ua0, ua1, la0, la1);
    __syncthreads();
    LOADAB(kk + 1, ab0, ab1, ub0, ub1, lb0, lb1);
    COMPUTEC();
    __syncthreads();
    STOREAB(ab0, ab1, ub0, ub1, lb0, lb1);
    __syncthreads();
    if (kk + 2 < 8) LOADAB(kk + 2, aa0, aa1, ua0, ua1, la0, la1);
    COMPUTEC();
  }
#undef LOADAB
#undef STOREAB
#undef COMPUTEC

  float bias[4];
  for (int r = 0; r < 4; ++r) bias[r] = bout[m0 + w * 16 + q * 4 + r];
  for (int n2 = 0; n2 < 2; ++n2) {
    int l = n0 + n2 * 16 + ln;
    for (int r = 0; r < 4; ++r) {
      int o = m0 + w * 16 + q * 4 + r;
      out[((size_t)b * Cn + o) * Ln + l] = acc[n2][r] + bias[r];
    }
  }
}

// ---------------- launch -----------------------------------------------------
extern "C" void kernel_launch(void* const* d_in, const int* in_sizes, int n_in,
                              void* d_out, int out_size, void* d_ws, size_t ws_size,
                              hipStream_t stream) {
  const float* x = (const float*)d_in[0];
  const float* wqkv = (const float*)d_in[1];
  const float* wout = (const float*)d_in[2];
  const float* bout = (const float*)d_in[3];
  float* out = (float*)d_out;
  char* ws = (char*)d_ws;

  u16* wq_b  = (u16*)(ws + 0);          // [1536][256] bf16          (786432)
  u16* wo_b  = (u16*)(ws + 786432);     // [256][512]  bf16          (262144)
  float* lP  = (float*)(ws + 1048576);  // [2][4][8][2048] f32       (524288)
  u16* qT    = (u16*)(ws + 1572864);    // [4][8][2048][64]          (8 MB)
  u16* kT    = (u16*)(ws + 9961472);    // [4][8][2048][64]          (8 MB)
  u16* vv    = (u16*)(ws + 18350080);   // [4][512][2048] (l-permuted) (8 MB)
  u16* xT    = (u16*)(ws + 26738688);   // [4][2048][256]            (4 MB)
  u16* pO    = (u16*)(ws + 26738688);   // [2][4][2048][512]         (16 MB)

  prep_all<<<2560, 256, 0, stream>>>(wqkv, wout, x, wq_b, wo_b, xT);
  qkv_gemm<<<dim3(32, 8, 4), 256, 0, stream>>>(wq_b, xT, qT, kT, vv);
  attention<<<dim3(16, 32, 2), 128, 0, stream>>>(qT, kT, vv, pO, lP);
  out_gemm<<<dim3(64, 4, 4), 256, 0, stream>>>(wo_b, pO, lP, bout, out);
}